// Round 5
// baseline (781.217 us; speedup 1.0000x reference)
//
#include <hip/hip_runtime.h>

// VecInt scaling-and-squaring. AoS fp32 layout [z][y][x][c] (c = z,y,x disp).
//
// R4 post-mortem: march_k matched step_k at 86us but with Occupancy 26% and no
// saturated pipe -> latency/serialization bound (3 blocks/CU with zero slack,
// 10-wave blocks, 46KB LDS) + 27 scalar ds_read_b32 per voxel (7.4M conflict
// cycles). R5: (1) ZCHUNK 20->10, grid 1536 for load balance; (2) float4-padded
// LDS voxels -> 9 aligned ds_read_b128 per voxel instead of 27 ds_read_b32;
// (3) 61.4KB LDS -> 2 blocks/CU (20 waves). Steps 6-7 keep global gather
// (|d| up to ~3 exceeds the +-1 window).

namespace {

constexpr int Dd = 160, Hh = 192, Ww = 160, Bb = 2;
constexpr int HW   = Hh * Ww;                 // 30720
constexpr int VOX  = Dd * HW;                 // 4,915,200 per batch
constexpr int NTOT = Bb * VOX;                // 9,830,400 voxels
constexpr long long NFLT = (long long)NTOT * 3;
constexpr int ROWF = Ww * 3;                  // 480 floats per (z,y) row

// ---- disp0 = vel / 128 ----
__global__ __launch_bounds__(256) void scale_k(const float* __restrict__ in,
                                               float* __restrict__ out) {
    long long i = (long long)blockIdx.x * blockDim.x + threadIdx.x;
    const long long n4 = NFLT / 4;
    if (i < n4) {
        float4 v = reinterpret_cast<const float4*>(in)[i];
        constexpr float s = 1.0f / 128.0f;
        v.x *= s; v.y *= s; v.z *= s; v.w *= s;
        reinterpret_cast<float4*>(out)[i] = v;
    }
}

// ---- global-gather step (steps 6,7) ----
__global__ __launch_bounds__(256) void step_k(const float* __restrict__ disp,
                                              float* __restrict__ out) {
    int idx = blockIdx.x * blockDim.x + threadIdx.x;
    if (idx >= NTOT) return;

    int b = (idx >= VOX) ? 1 : 0;
    int v = idx - b * VOX;
    int z = v / HW;
    int rem = v - z * HW;
    int y = rem / Ww;
    int x = rem - y * Ww;

    const float* __restrict__ vol = disp + (long long)b * VOX * 3;
    int base3 = idx * 3;
    float d0 = disp[base3 + 0];
    float d1 = disp[base3 + 1];
    float d2 = disp[base3 + 2];

    float lz = fminf(fmaxf((float)z + d0, 0.0f), (float)(Dd - 1));
    float ly = fminf(fmaxf((float)y + d1, 0.0f), (float)(Hh - 1));
    float lx = fminf(fmaxf((float)x + d2, 0.0f), (float)(Ww - 1));

    float fz = floorf(lz), fy = floorf(ly), fx = floorf(lx);
    int z0 = (int)fz, y0 = (int)fy, x0 = (int)fx;
    int z1 = min(z0 + 1, Dd - 1);
    int y1 = min(y0 + 1, Hh - 1);
    int x1 = min(x0 + 1, Ww - 1);
    float tz = lz - fz, ty = ly - fy, tx = lx - fx;
    float sz = 1.0f - tz, sy = 1.0f - ty, sx = 1.0f - tx;

    float w000 = sz * sy * sx, w001 = sz * sy * tx;
    float w010 = sz * ty * sx, w011 = sz * ty * tx;
    float w100 = tz * sy * sx, w101 = tz * sy * tx;
    float w110 = tz * ty * sx, w111 = tz * ty * tx;

    int r00 = (z0 * Hh + y0) * Ww;
    int r01 = (z0 * Hh + y1) * Ww;
    int r10 = (z1 * Hh + y0) * Ww;
    int r11 = (z1 * Hh + y1) * Ww;

    const float* p000 = vol + (r00 + x0) * 3;
    const float* p001 = vol + (r00 + x1) * 3;
    const float* p010 = vol + (r01 + x0) * 3;
    const float* p011 = vol + (r01 + x1) * 3;
    const float* p100 = vol + (r10 + x0) * 3;
    const float* p101 = vol + (r10 + x1) * 3;
    const float* p110 = vol + (r11 + x0) * 3;
    const float* p111 = vol + (r11 + x1) * 3;

    float a0 = w000 * p000[0] + w001 * p001[0] + w010 * p010[0] + w011 * p011[0]
             + w100 * p100[0] + w101 * p101[0] + w110 * p110[0] + w111 * p111[0];
    float a1 = w000 * p000[1] + w001 * p001[1] + w010 * p010[1] + w011 * p011[1]
             + w100 * p100[1] + w101 * p101[1] + w110 * p110[1] + w111 * p111[1];
    float a2 = w000 * p000[2] + w001 * p001[2] + w010 * p010[2] + w011 * p011[2]
             + w100 * p100[2] + w101 * p101[2] + w110 * p110[2] + w111 * p111[2];

    out[base3 + 0] = d0 + a0;
    out[base3 + 1] = d1 + a1;
    out[base3 + 2] = d2 + a2;
}

// ---- rolling z-march, float4-padded LDS, ds_read_b128 gathers (steps 1..5) --
template <int H, int TY, int ZCHUNK>
__global__ __launch_bounds__(TY * Ww) void march_k(const float* __restrict__ A,
                                                   float* __restrict__ B) {
    constexpr int R = TY + 2 * H;        // staged rows per plane slot (6)
    constexpr int W = 2 * H + 2;         // ring slots incl. prefetch spare (4)
    constexpr int RX = Ww;               // voxels per row
    constexpr int SLOTV = R * RX;        // voxels per slot (960)
    constexpr int NTHR = TY * Ww;        // block threads (640)
    __shared__ float4 lds4[W * SLOTV];   // 4*960*16 = 61,440 B -> 2 blocks/CU

    const int tid = threadIdx.x;
    const int ty0 = blockIdx.x * TY;     // y-tile base
    const int c0  = blockIdx.y * ZCHUNK; // z-chunk base
    const int b   = blockIdx.z;          // batch
    const int base3 = b * VOX * 3;

    const int x  = tid % Ww;
    const int ry = tid / Ww;             // 0..TY-1
    const int gy = ty0 + ry;

    const int ylo = max(ty0 - H, 0);
    const int yhi = min(ty0 + TY - 1 + H, Hh - 1);
    const int nv    = (yhi - ylo + 1) * RX;        // voxels to stage per plane
    const int voff  = (ylo - (ty0 - H)) * RX;      // LDS voxel offset

    // stage plane p into ring slot p%W (packed 12B global -> padded 16B LDS)
    auto stage = [&](int p) {
        if (p < 0 || p >= Dd) return;
        const float* src = A + base3 + (p * Hh + ylo) * ROWF;
        float4* dst = lds4 + (p % W) * SLOTV + voff;
        for (int v = tid; v < nv; v += NTHR) {
            int v3 = v * 3;
            dst[v] = make_float4(src[v3], src[v3 + 1], src[v3 + 2], 0.0f);
        }
    };

    for (int p = c0 - H; p <= c0 + H; ++p) stage(p);
    __syncthreads();

    const int zend = c0 + ZCHUNK;
    for (int z = c0; z < zend; ++z) {
        // prefetch next needed plane into the spare slot
        if (z + H + 1 <= zend) stage(z + H + 1);

        const int rowOwn = gy - (ty0 - H);
        float4 ownv = lds4[(z % W) * SLOTV + rowOwn * RX + x];
        float d0 = ownv.x, d1 = ownv.y, d2 = ownv.z;

        float lz = fminf(fmaxf((float)z + d0, 0.0f), (float)(Dd - 1));
        float ly = fminf(fmaxf((float)gy + d1, 0.0f), (float)(Hh - 1));
        float lx = fminf(fmaxf((float)x + d2, 0.0f), (float)(Ww - 1));

        float fz = floorf(lz), fy = floorf(ly), fx = floorf(lx);
        int z0 = (int)fz, y0 = (int)fy, x0 = (int)fx;
        int z1 = min(z0 + 1, Dd - 1);
        int y1 = min(y0 + 1, Hh - 1);
        int x1 = min(x0 + 1, Ww - 1);
        float tz = lz - fz, ty = ly - fy, tx = lx - fx;
        float sz = 1.0f - tz, sy = 1.0f - ty, sx = 1.0f - tx;

        float4 c000, c001, c010, c011, c100, c101, c110, c111;
        bool inw = (z0 >= z - H) && (z1 <= z + H) &&
                   (y0 >= ty0 - H) && (y1 <= ty0 + TY - 1 + H);
        if (inw) {
            int s0 = (z0 % W) * SLOTV;
            int s1 = (z1 % W) * SLOTV;
            int r00 = s0 + (y0 - (ty0 - H)) * RX;
            int r01 = s0 + (y1 - (ty0 - H)) * RX;
            int r10 = s1 + (y0 - (ty0 - H)) * RX;
            int r11 = s1 + (y1 - (ty0 - H)) * RX;
            c000 = lds4[r00 + x0]; c001 = lds4[r00 + x1];
            c010 = lds4[r01 + x0]; c011 = lds4[r01 + x1];
            c100 = lds4[r10 + x0]; c101 = lds4[r10 + x1];
            c110 = lds4[r11 + x0]; c111 = lds4[r11 + x1];
        } else {
            // rare fallback: |d| exceeded H; gather from global (exact math)
            const float* G = A + base3;
            const float* Q00 = G + (z0 * Hh + y0) * ROWF;
            const float* Q01 = G + (z0 * Hh + y1) * ROWF;
            const float* Q10 = G + (z1 * Hh + y0) * ROWF;
            const float* Q11 = G + (z1 * Hh + y1) * ROWF;
            int xa = x0 * 3, xb = x1 * 3;
            c000 = make_float4(Q00[xa], Q00[xa + 1], Q00[xa + 2], 0.f);
            c001 = make_float4(Q00[xb], Q00[xb + 1], Q00[xb + 2], 0.f);
            c010 = make_float4(Q01[xa], Q01[xa + 1], Q01[xa + 2], 0.f);
            c011 = make_float4(Q01[xb], Q01[xb + 1], Q01[xb + 2], 0.f);
            c100 = make_float4(Q10[xa], Q10[xa + 1], Q10[xa + 2], 0.f);
            c101 = make_float4(Q10[xb], Q10[xb + 1], Q10[xb + 2], 0.f);
            c110 = make_float4(Q11[xa], Q11[xa + 1], Q11[xa + 2], 0.f);
            c111 = make_float4(Q11[xb], Q11[xb + 1], Q11[xb + 2], 0.f);
        }

        float w000 = sz * sy * sx, w001 = sz * sy * tx;
        float w010 = sz * ty * sx, w011 = sz * ty * tx;
        float w100 = tz * sy * sx, w101 = tz * sy * tx;
        float w110 = tz * ty * sx, w111 = tz * ty * tx;

        float a0 = w000 * c000.x + w001 * c001.x + w010 * c010.x + w011 * c011.x
                 + w100 * c100.x + w101 * c101.x + w110 * c110.x + w111 * c111.x;
        float a1 = w000 * c000.y + w001 * c001.y + w010 * c010.y + w011 * c011.y
                 + w100 * c100.y + w101 * c101.y + w110 * c110.y + w111 * c111.y;
        float a2 = w000 * c000.z + w001 * c001.z + w010 * c010.z + w011 * c011.z
                 + w100 * c100.z + w101 * c101.z + w110 * c110.z + w111 * c111.z;

        float* o = B + base3 + (z * Hh + gy) * ROWF + x * 3;
        o[0] = d0 + a0;
        o[1] = d1 + a1;
        o[2] = d2 + a2;

        __syncthreads();
    }
}

}  // namespace

extern "C" void kernel_launch(void* const* d_in, const int* in_sizes, int n_in,
                              void* d_out, int out_size, void* d_ws, size_t ws_size,
                              hipStream_t stream) {
    const float* vel = (const float*)d_in[0];
    float* out = (float*)d_out;
    float* W   = (float*)d_ws;   // buffer A (118 MB)
    float* O   = (float*)d_out;  // buffer B = d_out doubles as scratch

    // disp0 = vel / 128 -> ws
    {
        long long n4 = NFLT / 4;
        int blk = 256;
        int grd = (int)((n4 + blk - 1) / blk);
        scale_k<<<grd, blk, 0, stream>>>(vel, W);
    }

    constexpr int TY = 4, ZCHUNK = 10;
    dim3 mgrid(Hh / TY, Dd / ZCHUNK, Bb);  // 48 x 16 x 2 = 1536 blocks
    int  mblk = TY * Ww;                   // 640 threads

    float* a = W;
    float* b = O;
    // steps 1..5: |d| < 0.75 -> H=1 march
    for (int it = 0; it < 5; ++it) {
        march_k<1, TY, ZCHUNK><<<mgrid, mblk, 0, stream>>>(a, b);
        float* t = a; a = b; b = t;
    }
    // steps 6,7: |d| up to ~3 -> global-gather kernel
    int blk = 256;
    int grd = (NTOT + blk - 1) / blk;
    for (int it = 0; it < 2; ++it) {
        step_k<<<grd, blk, 0, stream>>>(a, b);
        float* t = a; a = b; b = t;
    }
    // 7 steps total (odd) starting from ws -> final result lands in d_out.
}